// Round 10
// baseline (152.949 us; speedup 1.0000x reference)
//
#include <hip/hip_runtime.h>
#include <hip/hip_bf16.h>

typedef unsigned int u32;
typedef unsigned short u16;
typedef unsigned long long u64;
typedef __attribute__((ext_vector_type(8))) short short8;
typedef __attribute__((ext_vector_type(4))) float f32x4;

#define BATCH 4
#define SEQ   4096
#define DIM   768
#define HD    64
#define NROW  (BATCH*SEQ)   // 16384
#define LOG2E 1.44269504088896f
#define SSCALE (0.125f * LOG2E)
#define CSHIFT (-32.0f)      // fixed exp2-domain shift (softmax shift-invariant)
#define NEGBIG (-1.0e30f)
#define PSLOTB 4224          // partial slot: 4096 B bf16 O[32][64] + 128 B f32 l[32]
#define NSLOT  4352          // 4 batches x 136 chunk-slots x 8 (wave,halfpass)

__device__ __forceinline__ float ex2(float x) { return __builtin_amdgcn_exp2f(x); }
__device__ __forceinline__ float bfbits2f(u16 u) {
    return __uint_as_float(((u32)u) << 16);
}
__device__ __forceinline__ u16 f2bf(float f) {
    return (u16)((__float_as_uint(f) + 0x8000u) >> 16);
}
__device__ __forceinline__ u32 pkbf(float a, float b) { // lo16=bf(a), hi16=bf(b)
    u32 xa = __float_as_uint(a) + 0x8000u;
    u32 xb = __float_as_uint(b) + 0x8000u;
    return __builtin_amdgcn_perm(xb, xa, 0x07060302);
}
// Deterministic per-wave dtype sniff (same answer in every wave/block).
__device__ __forceinline__ int sniff_bf16(const u32* x) {
    u32 w = x[threadIdx.x & 63];
    u32 lo = w & 0xffffu;
    u32 e  = (lo >> 7) & 0xffu;
    bool ok = (lo == 0u) || (e >= 96u && e <= 134u);
    u64 bal = __ballot(ok);
    return (__popcll(bal) >= 48) ? 1 : 0;
}

// ---------------- W pre-conversion: fp32 -> bf16, ONCE ---------------------
__global__ __launch_bounds__(256) void wconv_kernel(
    const u32* __restrict__ xs,
    const void* __restrict__ wq, const void* __restrict__ wk,
    const void* __restrict__ wv, u16* __restrict__ wb)
{
    const int flag = sniff_bf16(xs);
    const int j = blockIdx.x * 256 + threadIdx.x;   // 0..18431
    const int e = j * 8;
    const int r = e / DIM;          // 0..191  ([wq;wk;wv] stacked)
    const int c = e - r * DIM;
    const void* src = (r < 64) ? wq : (r < 128) ? wk : wv;
    const long soff = (long)(r & 63) * DIM + c;
    if (flag) {
        *reinterpret_cast<short8*>(wb + (long)r * DIM + c) =
            *reinterpret_cast<const short8*>((const u16*)src + soff);
    } else {
        const float* p = (const float*)src + soff;
        float4 a = *reinterpret_cast<const float4*>(p);
        float4 d = *reinterpret_cast<const float4*>(p + 4);
        union { u32 u[4]; short8 s; } un;
        un.u[0] = pkbf(a.x, a.y); un.u[1] = pkbf(a.z, a.w);
        un.u[2] = pkbf(d.x, d.y); un.u[3] = pkbf(d.z, d.w);
        *reinterpret_cast<short8*>(wb + (long)r * DIM + c) = un.s;
    }
}

// ---------------- QKV projection: split-column LDS-tiled GEMM ---------------
// r8 had 258 blocks (~1/CU): barrier drains fully exposed. Now each 64-row
// stripe is TWO blocks (ch = bid&1) of 96 cols -> 514 blocks (~2/CU), so a
// second block backfills every stall. Sibling blocks share X rows (L2-hit on
// the 2nd read). LDS 28.4 KB: X 8 KB + W 12 KB + Vt 8.4 KB.
// ch=0: q (cols 0-63) + k cols 0-31; ch=1: k cols 32-63 + v.
// K and V written in MFMA-FRAGMENT-MAJOR tile layout (harness-verified r8):
//   element (m, lane l, elem e) at tile*4096 + m*512 + l*8 + e (u16)
//   K: row=16s+(l&15), col=32h+8*(l>>4)+e, m=2s+h
//   V: dim d=16*(m>>1)+(l&15), seqpos kk=32*(m&1)+8*(l>>4)+e
__global__ __launch_bounds__(512, 4) void qkv_kernel(
    const void* __restrict__ x, const u16* __restrict__ wb,
    const int* __restrict__ mask,
    u16* __restrict__ qws, u16* __restrict__ kws, u16* __restrict__ vpws,
    u32* __restrict__ mb)
{
    const int t = threadIdx.x;
    const int l = t & 63;
    const int w = t >> 6;

    if (blockIdx.x >= 512) {            // ---- mask bit-pack ----
        const int base = (blockIdx.x - 512) * 8192 + w * 1024;
#pragma unroll
        for (int it = 0; it < 16; ++it) {
            const int idx = base + it * 64 + l;
            u64 bal = __ballot(mask[idx] != 0);
            if (l == 0)       mb[idx >> 5] = (u32)bal;
            else if (l == 32) mb[idx >> 5] = (u32)(bal >> 32);
        }
        return;
    }

    const int flag = sniff_bf16((const u32*)x);
    __shared__ __align__(16) u16 Xl[64 * 64];    // 8 KB,  slot r*64 + cc*8
    __shared__ __align__(16) u16 Wl[96 * 64];    // 12 KB, slot n*64 + cc*8
    __shared__ u16 Vt[64][66];                   // 8.4 KB transpose staging (ch=1)

    const int li = l & 15;
    const int g  = l >> 4;
    const int g4 = g * 4;
    const int strip = w & 3;            // 16-row strip
    const int nhalf = w >> 2;           // 48-col half (0..1)
    const int tile = blockIdx.x >> 1;   // 0..255: 64-row stripe
    const int ch   = blockIdx.x & 1;    // column half of the 192
    const int m0 = tile * 64;
    const int b  = m0 >> 12;

    auto ldbf = [&](const void* bp, long off) -> short8 {
        if (flag) return *reinterpret_cast<const short8*>((const u16*)bp + off);
        const float* p = (const float*)bp + off;
        float4 a = *reinterpret_cast<const float4*>(p);
        float4 c = *reinterpret_cast<const float4*>(p + 4);
        union { u32 u[4]; short8 s; } un;
        un.u[0] = pkbf(a.x, a.y); un.u[1] = pkbf(a.z, a.w);
        un.u[2] = pkbf(c.x, c.y); un.u[3] = pkbf(c.z, c.w);
        return un.s;
    };

    // staging maps (kc-invariant)
    const int xr = t >> 3, xcc = t & 7, xc = xcc ^ (xr & 7);
    const long xsoff = (long)(m0 + xr) * DIM + xc * 8;
    const int r0 = t >> 3, cc0 = t & 7, c0 = cc0 ^ (r0 & 7);
    const long wboff0 = (long)(ch * 96 + r0) * DIM + c0 * 8;
    const int wdst0 = t * 8;
    const bool w1 = (t < 256);          // wave-uniform (waves 0-3)
    const int idx1 = 512 + t;
    const int r1 = idx1 >> 3, cc1 = idx1 & 7, c1 = cc1 ^ (r1 & 7);
    const long wboff1 = (long)(ch * 96 + (r1 & 127)) * DIM + c1 * 8;  // r1<96 when w1
    const int wdst1 = idx1 * 8;

    // fragment read offsets
    const int am = strip * 16 + li;
    const int a0off = am * 64 + ((g       ^ (am & 7)) * 8);
    const int a1off = am * 64 + (((g | 4) ^ (am & 7)) * 8);
    int boff[6];
#pragma unroll
    for (int ns = 0; ns < 3; ++ns) {
        const int nl = nhalf * 48 + ns * 16 + li;
        boff[2*ns]   = nl * 64 + ((g       ^ (nl & 7)) * 8);
        boff[2*ns+1] = nl * 64 + (((g | 4) ^ (nl & 7)) * 8);
    }

    f32x4 acc[3];
#pragma unroll
    for (int i = 0; i < 3; ++i) acc[i] = (f32x4){0.f, 0.f, 0.f, 0.f};

    short8 xs  = ldbf(x, xsoff);
    short8 ws0 = *reinterpret_cast<const short8*>(wb + wboff0);
    short8 ws1 = {};
    if (w1) ws1 = *reinterpret_cast<const short8*>(wb + wboff1);

    for (int kc = 0; kc < 12; ++kc) {
        __syncthreads();                 // previous K-step's LDS reads done
        *reinterpret_cast<short8*>(&Xl[t * 8])   = xs;
        *reinterpret_cast<short8*>(&Wl[wdst0])   = ws0;
        if (w1) *reinterpret_cast<short8*>(&Wl[wdst1]) = ws1;
        if (kc < 11) {                   // prefetch next staging tile
            const long o = (long)(kc + 1) * 64;
            xs  = ldbf(x, xsoff + o);
            ws0 = *reinterpret_cast<const short8*>(wb + wboff0 + o);
            if (w1) ws1 = *reinterpret_cast<const short8*>(wb + wboff1 + o);
        }
        __syncthreads();                 // staging visible
        short8 af0 = *reinterpret_cast<const short8*>(&Xl[a0off]);
        short8 af1 = *reinterpret_cast<const short8*>(&Xl[a1off]);
#pragma unroll
        for (int ns = 0; ns < 3; ++ns) {
            short8 b0 = *reinterpret_cast<const short8*>(&Wl[boff[2*ns]]);
            short8 b1 = *reinterpret_cast<const short8*>(&Wl[boff[2*ns+1]]);
            acc[ns] = __builtin_amdgcn_mfma_f32_16x16x32_bf16(af0, b0, acc[ns], 0, 0, 0);
            acc[ns] = __builtin_amdgcn_mfma_f32_16x16x32_bf16(af1, b1, acc[ns], 0, 0, 0);
        }
    }

    // epilogue: q row-major; K fragment-major; V via LDS transpose
#pragma unroll
    for (int ns = 0; ns < 3; ++ns) {
        const int n = ch * 96 + nhalf * 48 + ns * 16 + li;
#pragma unroll
        for (int r = 0; r < 4; ++r) {
            const int rowl = strip * 16 + g4 + r;
            u16 bv = f2bf(acc[ns][r]);
            if (n < 64) {
                qws[(long)(m0 + rowl) * HD + n] = bv;
            } else if (n < 128) {
                const int col = n - 64;                  // 0..63
                const int j   = 2 * strip + (col >> 5);  // m index
                const int gg  = (col >> 3) & 3;
                const int e   = col & 7;
                kws[(long)tile * 4096 + j * 512 + (gg * 16 + (g4 + r)) * 8 + e] = bv;
            } else {
                Vt[rowl][n - 128] = bv;
            }
        }
    }
    __syncthreads();
    if (ch == 1) {   // V out in fragment-major layout
        const int d  = t >> 3;   // 0..63
        const int mg = t & 7;    // 0..7
        union { u16 h[8]; short8 s; } u;
#pragma unroll
        for (int i = 0; i < 8; ++i) u.h[i] = Vt[mg * 8 + i][d];
        const int m  = 2 * (d >> 4) + (mg >> 2);
        const int lq = (mg & 3) * 16 + (d & 15);
        u16* dst = vpws + (long)tile * 4096 + m * 512 + lq * 8;
        *reinterpret_cast<short8*>(dst) = u.s;
    }
}

// ---------------- Flash attention: 64 q-rows/wave, uniform 4-tile chunks ---
// r7 structure (64 q-rows/wave, 4-wave convoy, single Ps buffer, single-ka
// pipeline, coalesced fragment-major K/V) with the k-range now split into
// chunks of exactly 4 k-tiles: nkt = 4*qt256+4 so EVERY block runs ntile=4
// (perfect balance) and the grid becomes 544 (~2.1 blocks/CU; r7's 288 was
// ~1/CU -> Occupancy 8%, all stalls exposed).
// Triangular (qt256, c) decode is pure-integer (no device libm).
__global__ __launch_bounds__(256, 2) void attn_kernel(
    const u32* __restrict__ xs,
    const u16* __restrict__ qw, const u16* __restrict__ kw,
    const u16* __restrict__ vpw, const u32* __restrict__ maskbits,
    char* __restrict__ part, void* __restrict__ out)
{
    __shared__ __align__(16) u16 Ps[4][4][16][72];   // 36.9 KB, per-wave regions

    const int flag = sniff_bf16(xs);
    const int t  = threadIdx.x;
    const int l  = t & 63;
    const int w  = t >> 6;
    const int li = l & 15;
    const int g  = l >> 4;
    const int g4 = g * 4;

    // XCD-affine decode: b = (bid%8)>>1; s = per-batch task 0..135.
    const int bid = blockIdx.x;          // grid = 544
    const int b   = (bid & 7) >> 1;
    const int s   = (bid >> 3) * 2 + (bid & 1);
    // integer triangular decode: qt256 = max n in [0,15] with n(n+1)/2 <= s
    int qt256 = 0;
#pragma unroll
    for (int n = 1; n < 16; ++n)
        qt256 = (n * (n + 1) / 2 <= s) ? n : qt256;
    const int c     = s - qt256 * (qt256 + 1) / 2;   // 0..qt256
    const int ktBeg = c * 4;
    const bool single = (qt256 == 0);    // nc==1 -> direct out write
    const int q0     = qt256 * 256 + w * 64;  // this wave's 64 q rows

    const u16* qrow = qw + ((long)(b * SEQ + q0 + li)) * HD + g * 8;
    short8 qf0 = *reinterpret_cast<const short8*>(qrow);
    short8 qf1 = *reinterpret_cast<const short8*>(qrow + 32);
    short8 qf2 = *reinterpret_cast<const short8*>(qrow + 16 * HD);
    short8 qf3 = *reinterpret_cast<const short8*>(qrow + 16 * HD + 32);
    short8 qf4 = *reinterpret_cast<const short8*>(qrow + 32 * HD);
    short8 qf5 = *reinterpret_cast<const short8*>(qrow + 32 * HD + 32);
    short8 qf6 = *reinterpret_cast<const short8*>(qrow + 48 * HD);
    short8 qf7 = *reinterpret_cast<const short8*>(qrow + 48 * HD + 32);

    short8 ones;
#pragma unroll
    for (int i = 0; i < 8; ++i) ones[i] = (short)0x3F80;  // bf16 1.0

    f32x4 O[16];
#pragma unroll
    for (int i = 0; i < 16; ++i) O[i] = (f32x4){0.f, 0.f, 0.f, 0.f};
    f32x4 l4A = (f32x4){0.f, 0.f, 0.f, 0.f};
    f32x4 l4B = (f32x4){0.f, 0.f, 0.f, 0.f};
    f32x4 l4C = (f32x4){0.f, 0.f, 0.f, 0.f};
    f32x4 l4D = (f32x4){0.f, 0.f, 0.f, 0.f};
    const int qgA = q0 + li;
    const int qgB = q0 + 16 + li;
    const int qgC = q0 + 32 + li;
    const int qgD = q0 + 48 + li;
    const f32x4 z4 = (f32x4){0.f, 0.f, 0.f, 0.f};

    // fragment-major tile bases: + l*8 makes every load lane-linear (16B/lane)
    const u16* kbase = kw  + (long)(b * 64) * 4096 + l * 8;
    const u16* vbase = vpw + (long)(b * 64) * 4096 + l * 8;

    short8 ka[8];
    short8 vf[8];
    auto kload = [&](int i) {                     // tile idx 0..3
        const u16* kp = kbase + (long)(ktBeg + i) * 4096;
#pragma unroll
        for (int m = 0; m < 8; ++m)
            ka[m] = *reinterpret_cast<const short8*>(kp + m * 512);
    };
    auto vfload = [&](int i) {
        const u16* vr = vbase + (long)(ktBeg + i) * 4096;
#pragma unroll
        for (int m = 0; m < 8; ++m)
            vf[m] = *reinterpret_cast<const short8*>(vr + m * 512);
    };
    auto sphase = [&](int i) {            // S^T + softmax -> Ps[w][qs], 4 subtiles
        const int k0 = (ktBeg + i) * 64;
        const u32 mb0 = maskbits[b * 128 + (k0 >> 5)];
        const u32 mb1 = maskbits[b * 128 + (k0 >> 5) + 1];
#pragma unroll
        for (int sub = 0; sub < 4; ++sub) {
            const u32 word = (sub & 2) ? mb1 : mb0;
            const int klb = k0 + sub * 16 + g4;
            const int sh  = (sub & 1) * 16 + g4;
            // subtile A
            {
                f32x4 a = __builtin_amdgcn_mfma_f32_16x16x32_bf16(ka[2*sub],   qf0, z4, 0, 0, 0);
                a       = __builtin_amdgcn_mfma_f32_16x16x32_bf16(ka[2*sub+1], qf1, a,  0, 0, 0);
                float p[4];
#pragma unroll
                for (int r = 0; r < 4; ++r) {
                    const bool keep = ((klb + r) <= qgA) && (((word >> (sh + r)) & 1u) != 0u);
                    p[r] = ex2(fmaf(a[r], SSCALE, keep ? CSHIFT : NEGBIG));
                }
                *reinterpret_cast<uint2*>(&Ps[w][0][li][sub * 16 + g4]) =
                    make_uint2(pkbf(p[0], p[1]), pkbf(p[2], p[3]));
            }
            // subtile B
            {
                f32x4 a = __builtin_amdgcn_mfma_f32_16x16x32_bf16(ka[2*sub],   qf2, z4, 0, 0, 0);
                a       = __builtin_amdgcn_mfma_f32_16x16x32_bf16(ka[2*sub+1], qf3, a,  0, 0, 0);
                float p[4];
#pragma unroll
                for (int r = 0; r < 4; ++r) {
                    const bool keep = ((klb + r) <= qgB) && (((word >> (sh + r)) & 1u) != 0u);
                    p[r] = ex2(fmaf(a[r], SSCALE, keep ? CSHIFT : NEGBIG));
                }
                *reinterpret_cast<uint2*>(&Ps[w][1][li][sub * 16 + g4]) =
                    make_uint2(pkbf(p[0], p[1]), pkbf(p[2], p[3]));
            }
            // subtile C
            {
                f32x4 a = __builtin_amdgcn_mfma_f32_16x16x32_bf16(ka[2*sub],   qf4, z4, 0, 0, 0);
                a       = __builtin_amdgcn_mfma_f32_16x16x32_bf16(ka[2*sub+1], qf5, a,  0, 0, 0);
                float p[4];
#pragma unroll
                for (int r = 0; r < 4; ++r) {
                    const bool keep = ((klb + r) <= qgC) && (((word >> (sh + r)) & 1u) != 0u);
                    p[r] = ex2(fmaf(a[r], SSCALE, keep ? CSHIFT : NEGBIG));
                }
                *reinterpret_cast<uint2*>(&Ps[w][2][li][sub * 16 + g4]) =
                    make_uint2(pkbf(p[0], p[1]), pkbf(p[2], p[3]));
            }
            // subtile D
            {
                f32x4 a = __builtin_amdgcn_mfma_f32_16x16x32_bf16(ka[2*sub],   qf6, z4, 0, 0, 0);
                a       = __builtin_amdgcn_mfma_f32_16x16x32_bf16(ka[2*sub+1], qf7, a,  0, 0, 0);
                float p[4];
#pragma unroll
                for (int r = 0; r < 4; ++r) {
                    const bool keep = ((klb + r) <= qgD) && (((word >> (sh + r)) & 1u) != 0u);
                    p[r] = ex2(fmaf(a[r], SSCALE, keep ? CSHIFT : NEGBIG));
                }
                *reinterpret_cast<uint2*>(&Ps[w][3][li][sub * 16 + g4]) =
                    make_uint2(pkbf(p[0], p[1]), pkbf(p[2], p[3]));
            }
        }
    };

    kload(0);
    sphase(0);
    kload(1);
    for (int i = 0; i < 4; ++i) {
        __builtin_amdgcn_s_barrier();   // convoy: keep 4 waves on same tile
        vfload(i);
        short8 A1A = *reinterpret_cast<const short8*>(&Ps[w][0][li][g * 8]);
        short8 A2A = *reinterpret_cast<const short8*>(&Ps[w][0][li][32 + g * 8]);
        short8 A1B = *reinterpret_cast<const short8*>(&Ps[w][1][li][g * 8]);
        short8 A2B = *reinterpret_cast<const short8*>(&Ps[w][1][li][32 + g * 8]);
        short8 A1C = *reinterpret_cast<const short8*>(&Ps[w][2][li][g * 8]);
        short8 A2C = *reinterpret_cast<const short8*>(&Ps[w][2][li][32 + g * 8]);
        short8 A1D = *reinterpret_cast<const short8*>(&Ps[w][3][li][g * 8]);
        short8 A2D = *reinterpret_cast<const short8*>(&Ps[w][3][li][32 + g * 8]);
        if (i < 3) {
            sphase(i + 1);               // overwrites Ps AFTER the reg-reads above
            if (i < 2) kload(i + 2);     // refill single K buffer
        }
        f32x4 lt;
        lt = __builtin_amdgcn_mfma_f32_16x16x32_bf16(A1A, ones, z4, 0, 0, 0);
        lt = __builtin_amdgcn_mfma_f32_16x16x32_bf16(A2A, ones, lt, 0, 0, 0);
#pragma unroll
        for (int r = 0; r < 4; ++r) l4A[r] += lt[r];
        lt = __builtin_amdgcn_mfma_f32_16x16x32_bf16(A1B, ones, z4, 0, 0, 0);
        lt = __builtin_amdgcn_mfma_f32_16x16x32_bf16(A2B, ones, lt, 0, 0, 0);
#pragma unroll
        for (int r = 0; r < 4; ++r) l4B[r] += lt[r];
        lt = __builtin_amdgcn_mfma_f32_16x16x32_bf16(A1C, ones, z4, 0, 0, 0);
        lt = __builtin_amdgcn_mfma_f32_16x16x32_bf16(A2C, ones, lt, 0, 0, 0);
#pragma unroll
        for (int r = 0; r < 4; ++r) l4C[r] += lt[r];
        lt = __builtin_amdgcn_mfma_f32_16x16x32_bf16(A1D, ones, z4, 0, 0, 0);
        lt = __builtin_amdgcn_mfma_f32_16x16x32_bf16(A2D, ones, lt, 0, 0, 0);
#pragma unroll
        for (int r = 0; r < 4; ++r) l4D[r] += lt[r];
#pragma unroll
        for (int ds = 0; ds < 4; ++ds) {
            O[ds]      = __builtin_amdgcn_mfma_f32_16x16x32_bf16(A1A, vf[2*ds],   O[ds],      0, 0, 0);
            O[ds]      = __builtin_amdgcn_mfma_f32_16x16x32_bf16(A2A, vf[2*ds+1], O[ds],      0, 0, 0);
            O[4 + ds]  = __builtin_amdgcn_mfma_f32_16x16x32_bf16(A1B, vf[2*ds],   O[4 + ds],  0, 0, 0);
            O[4 + ds]  = __builtin_amdgcn_mfma_f32_16x16x32_bf16(A2B, vf[2*ds+1], O[4 + ds],  0, 0, 0);
            O[8 + ds]  = __builtin_amdgcn_mfma_f32_16x16x32_bf16(A1C, vf[2*ds],   O[8 + ds],  0, 0, 0);
            O[8 + ds]  = __builtin_amdgcn_mfma_f32_16x16x32_bf16(A2C, vf[2*ds+1], O[8 + ds],  0, 0, 0);
            O[12 + ds] = __builtin_amdgcn_mfma_f32_16x16x32_bf16(A1D, vf[2*ds],   O[12 + ds], 0, 0, 0);
            O[12 + ds] = __builtin_amdgcn_mfma_f32_16x16x32_bf16(A2D, vf[2*ds+1], O[12 + ds], 0, 0, 0);
        }
    }

    // ---- per-wave epilogue: two 32-row passes through this wave's Ps region ----
    {
        float* Of = reinterpret_cast<float*>(&Ps[w][0][0][0]);
        float* Lf = Of + 2112;
        const int r32 = l >> 1;          // 0..31: output row within pass
        const int h   = l & 1;           // column half (32 cols)
#pragma unroll
        for (int p = 0; p < 2; ++p) {
#pragma unroll
            for (int tile = 0; tile < 2; ++tile)
#pragma unroll
                for (int ds = 0; ds < 4; ++ds)
#pragma unroll
                    for (int r = 0; r < 4; ++r)
                        Of[(tile * 16 + g4 + r) * 66 + ds * 16 + li] =
                            O[(p * 2 + tile) * 4 + ds][r];
            if (li == 0) {
#pragma unroll
                for (int r = 0; r < 4; ++r) {
                    Lf[g4 + r]      = p ? l4C[r] : l4A[r];
                    Lf[16 + g4 + r] = p ? l4D[r] : l4B[r];
                }
            }
            float v[32];
#pragma unroll
            for (int j = 0; j < 8; ++j) {
                float4 f = *reinterpret_cast<const float4*>(&Of[r32 * 66 + h * 32 + j * 4]);
                v[4*j] = f.x; v[4*j+1] = f.y; v[4*j+2] = f.z; v[4*j+3] = f.w;
            }
            if (single) {
                const float L = Lf[r32];
                const float rl = (L > 0.f) ? 1.f / L : 0.f;
#pragma unroll
                for (int j = 0; j < 32; ++j) v[j] *= rl;
                const long row = (long)(b * SEQ + q0 + p * 32 + r32);
                if (flag) {
                    u16* dst = (u16*)out + row * HD + h * 32;
#pragma unroll
                    for (int jj = 0; jj < 4; ++jj) {
                        uint4 st = make_uint4(pkbf(v[8*jj],   v[8*jj+1]), pkbf(v[8*jj+2], v[8*jj+3]),
                                              pkbf(v[8*jj+4], v[8*jj+5]), pkbf(v[8*jj+6], v[8*jj+7]));
                        *reinterpret_cast<uint4*>(dst + jj * 8) = st;
                    }
                } else {
                    float* dst = (float*)out + row * HD + h * 32;
#pragma unroll
                    for (int jj = 0; jj < 8; ++jj)
                        *reinterpret_cast<float4*>(dst + jj * 4) =
                            make_float4(v[4*jj], v[4*jj+1], v[4*jj+2], v[4*jj+3]);
                }
            } else {
                const int slotIdx =
                    ((b * 136 + qt256 * (qt256 + 1) / 2 + c) * 8 + w * 2 + p);
                char* slot = part + (long)slotIdx * PSLOTB;
                u16* dst = (u16*)slot + r32 * 64 + h * 32;
#pragma unroll
                for (int jj = 0; jj < 4; ++jj) {
                    uint4 st = make_uint4(pkbf(v[8*jj],   v[8*jj+1]), pkbf(v[8*jj+2], v[8*jj+3]),
                                          pkbf(v[8*jj+4], v[8*jj+5]), pkbf(v[8*jj+6], v[8*jj+7]));
                    *reinterpret_cast<uint4*>(dst + jj * 8) = st;
                }
                if (l < 32)
                    *reinterpret_cast<float*>(slot + 4096 + l * 4) = Lf[l];
            }
        }
    }
}

// ---------------- merge split-K partials (qt256 >= 1): plain sum ----------
__global__ __launch_bounds__(256) void merge_kernel(
    const u32* __restrict__ xs, const char* __restrict__ part,
    void* __restrict__ out)
{
    const int flag = sniff_bf16(xs);
    const int bid = blockIdx.x;         // 480
    const int b = bid & 3;
    const int u = bid >> 2;             // 0..119
    const int qt256 = 1 + u / 8;        // 1..15
    const int v8 = u % 8;
    const int w = v8 >> 1;              // wave 0..3
    const int p = v8 & 1;               // half-pass 0..1
    const int nc = qt256 + 1;           // 2..16 chunks
    const int t  = threadIdx.x;
    const int qq = t >> 3;              // 0..31
    const int dd = (t & 7) * 8;         // 0..56
    const char* s0 = part +
        ((long)((b * 136 + qt256 * (qt256 + 1) / 2) * 8 + w * 2 + p)) * PSLOTB;
    float L = 0.f;
    float a8[8];
#pragma unroll
    for (int j = 0; j < 8; ++j) a8[j] = 0.f;
    for (int c = 0; c < nc; ++c) {
        const char* sc = s0 + (long)c * 8 * PSLOTB;   // c-stride = 8 slots
        L += *reinterpret_cast<const float*>(sc + 4096 + qq * 4);
        ushort4 x0 = *reinterpret_cast<const ushort4*>((const u16*)sc + qq * 64 + dd);
        ushort4 x1 = *reinterpret_cast<const ushort4*>((const u16*)sc + qq * 64 + dd + 4);
        a8[0] += bfbits2f(x0.x); a8[1] += bfbits2f(x0.y);
        a8[2] += bfbits2f(x0.z); a8[3] += bfbits2f(x0.w);
        a8[4] += bfbits2f(x1.x); a8[5] += bfbits2f(x1.y);
        a8[6] += bfbits2f(x1.z); a8[7] += bfbits2f(x1.w);
    }
    const float rl = (L > 0.f) ? 1.f / L : 0.f;
#pragma unroll
    for (int j = 0; j < 8; ++j) a8[j] *= rl;
    const long row = (long)(b * SEQ + qt256 * 256 + w * 64 + p * 32 + qq);
    if (flag) {
        uint4 st = make_uint4(pkbf(a8[0], a8[1]), pkbf(a8[2], a8[3]),
                              pkbf(a8[4], a8[5]), pkbf(a8[6], a8[7]));
        *reinterpret_cast<uint4*>((u16*)out + row * HD + dd) = st;
    } else {
        *reinterpret_cast<float4*>((float*)out + row * HD + dd) =
            make_float4(a8[0], a8[1], a8[2], a8[3]);
        *reinterpret_cast<float4*>((float*)out + row * HD + dd + 4) =
            make_float4(a8[4], a8[5], a8[6], a8[7]);
    }
}

extern "C" void kernel_launch(void* const* d_in, const int* in_sizes, int n_in,
                              void* d_out, int out_size, void* d_ws, size_t ws_size,
                              hipStream_t stream) {
    const void* x   = d_in[0];
    const int* mask = (const int*)d_in[1];
    const void* wq  = d_in[2];
    const void* wk  = d_in[3];
    const void* wv  = d_in[4];
    const u32* xs   = (const u32*)x;

    u16* q    = (u16*)d_ws;                          // 2 MB
    u16* k    = q  + (long)NROW * HD;                // 2 MB (fragment-major tiles)
    u16* vp   = k  + (long)NROW * HD;                // 2 MB (fragment-major tiles)
    u32* mb   = (u32*)(vp + (long)NROW * HD);        // 2 KB
    char* part = (char*)(mb + 512);                  // 4352 slots = 18.4 MB
    u16* wb   = (u16*)(part + (long)NSLOT * PSLOTB); // 288 KB bf16 W

    wconv_kernel<<<72, 256, 0, stream>>>(xs, wq, wk, wv, wb);
    qkv_kernel  <<<514, 512, 0, stream>>>(x, wb, mask, q, k, vp, mb);
    attn_kernel <<<544, 256, 0, stream>>>(xs, q, k, vp, mb, part, d_out);
    merge_kernel<<<480, 256, 0, stream>>>(xs, part, d_out);
}

// Round 11
// 140.386 us; speedup vs baseline: 1.0895x; 1.0895x over previous
//
#include <hip/hip_runtime.h>
#include <hip/hip_bf16.h>

typedef unsigned int u32;
typedef unsigned short u16;
typedef unsigned long long u64;
typedef __attribute__((ext_vector_type(8))) short short8;
typedef __attribute__((ext_vector_type(4))) float f32x4;

#define BATCH 4
#define SEQ   4096
#define DIM   768
#define HD    64
#define NROW  (BATCH*SEQ)   // 16384
#define LOG2E 1.44269504088896f
#define SSCALE (0.125f * LOG2E)
#define CSHIFT (-32.0f)      // fixed exp2-domain shift (softmax shift-invariant)
#define NEGBIG (-1.0e30f)
#define PSLOTB 4224          // partial slot: 4096 B bf16 O[32][64] + 128 B f32 l[32]
#define NSLOT  2304          // 4 batches x 72 chunk-slots x 8 (wave,halfpass)

__device__ __forceinline__ float ex2(float x) { return __builtin_amdgcn_exp2f(x); }
__device__ __forceinline__ float bfbits2f(u16 u) {
    return __uint_as_float(((u32)u) << 16);
}
__device__ __forceinline__ u16 f2bf(float f) {
    return (u16)((__float_as_uint(f) + 0x8000u) >> 16);
}
__device__ __forceinline__ u32 pkbf(float a, float b) { // lo16=bf(a), hi16=bf(b)
    u32 xa = __float_as_uint(a) + 0x8000u;
    u32 xb = __float_as_uint(b) + 0x8000u;
    return __builtin_amdgcn_perm(xb, xa, 0x07060302);
}
// Deterministic per-wave dtype sniff (same answer in every wave/block).
__device__ __forceinline__ int sniff_bf16(const u32* x) {
    u32 w = x[threadIdx.x & 63];
    u32 lo = w & 0xffffu;
    u32 e  = (lo >> 7) & 0xffu;
    bool ok = (lo == 0u) || (e >= 96u && e <= 134u);
    u64 bal = __ballot(ok);
    return (__popcll(bal) >= 48) ? 1 : 0;
}
// chunk-slot prefix for qt256 (256-row q tiles, chunks of 8 k-tiles):
// nchunk(j) = (j>>1)+1; off(n) = h*(h-1+(n&1)) + n, h=n>>1. Total 72/batch.
__device__ __forceinline__ int chunk_off(int n) {
    const int h = n >> 1;
    return h * (h - 1 + (n & 1)) + n;
}

// ---------------- W pre-conversion: fp32 -> bf16, ONCE ---------------------
__global__ __launch_bounds__(256) void wconv_kernel(
    const u32* __restrict__ xs,
    const void* __restrict__ wq, const void* __restrict__ wk,
    const void* __restrict__ wv, u16* __restrict__ wb)
{
    const int flag = sniff_bf16(xs);
    const int j = blockIdx.x * 256 + threadIdx.x;   // 0..18431
    const int e = j * 8;
    const int r = e / DIM;          // 0..191  ([wq;wk;wv] stacked)
    const int c = e - r * DIM;
    const void* src = (r < 64) ? wq : (r < 128) ? wk : wv;
    const long soff = (long)(r & 63) * DIM + c;
    if (flag) {
        *reinterpret_cast<short8*>(wb + (long)r * DIM + c) =
            *reinterpret_cast<const short8*>((const u16*)src + soff);
    } else {
        const float* p = (const float*)src + soff;
        float4 a = *reinterpret_cast<const float4*>(p);
        float4 d = *reinterpret_cast<const float4*>(p + 4);
        union { u32 u[4]; short8 s; } un;
        un.u[0] = pkbf(a.x, a.y); un.u[1] = pkbf(a.z, a.w);
        un.u[2] = pkbf(d.x, d.y); un.u[3] = pkbf(d.z, d.w);
        *reinterpret_cast<short8*>(wb + (long)r * DIM + c) = un.s;
    }
}

// ---------------- QKV projection: LDS-tiled GEMM (m97 shape) ----------------
// K and V are written in MFMA-FRAGMENT-MAJOR TILE LAYOUT: per 64x64 tile,
// element for (load-instruction m, lane l, elem e) sits at
// tile*4096 + m*512 + l*8 + e (u16). attn's kload/vfload then become 8 fully
// coalesced 1KB loads per tile (64 lanes x 16B contiguous) instead of 16
// scattered-row transactions per instruction (the r0-r7 ~2.6us/block-iter
// invariant was scattered line-request processing in the TA/L1 path).
//   K: row=16s+(l&15), col=32h+8*(l>>4)+e, m=2s+h
//   V: dim d=16*(m>>1)+(l&15), seqpos kk=32*(m&1)+8*(l>>4)+e
// NOTE (r10): splitting this kernel into 514 half-column blocks REGRESSED
// (~+5us): halving per-block MFMA while keeping full X staging doubled the
// X-issue. Keep monolithic 258-block form (best-measured, 139.7us total).
__global__ __launch_bounds__(512, 4) void qkv_kernel(
    const void* __restrict__ x, const u16* __restrict__ wb,
    const int* __restrict__ mask,
    u16* __restrict__ qws, u16* __restrict__ kws, u16* __restrict__ vpws,
    u32* __restrict__ mb)
{
    const int t = threadIdx.x;
    const int l = t & 63;
    const int w = t >> 6;

    if (blockIdx.x >= 256) {            // ---- mask bit-pack ----
        const int base = (blockIdx.x - 256) * 8192 + w * 1024;
#pragma unroll
        for (int it = 0; it < 16; ++it) {
            const int idx = base + it * 64 + l;
            u64 bal = __ballot(mask[idx] != 0);
            if (l == 0)       mb[idx >> 5] = (u32)bal;
            else if (l == 32) mb[idx >> 5] = (u32)(bal >> 32);
        }
        return;
    }

    const int flag = sniff_bf16((const u32*)x);
    __shared__ __align__(16) u16 Xl[64 * 64];    // 8 KB,  slot r*64 + cc*8
    __shared__ __align__(16) u16 Wl[192 * 64];   // 24 KB, slot n*64 + cc*8
    __shared__ u16 Vt[64][66];                   // 8.4 KB transpose staging

    const int li = l & 15;
    const int g  = l >> 4;
    const int g4 = g * 4;
    const int strip = w & 3;            // 16-row strip
    const int nhalf = w >> 2;           // 96-col half
    const int m0 = blockIdx.x * 64;
    const int b  = m0 >> 12;

    auto ldbf = [&](const void* bp, long off) -> short8 {
        if (flag) return *reinterpret_cast<const short8*>((const u16*)bp + off);
        const float* p = (const float*)bp + off;
        float4 a = *reinterpret_cast<const float4*>(p);
        float4 c = *reinterpret_cast<const float4*>(p + 4);
        union { u32 u[4]; short8 s; } un;
        un.u[0] = pkbf(a.x, a.y); un.u[1] = pkbf(a.z, a.w);
        un.u[2] = pkbf(c.x, c.y); un.u[3] = pkbf(c.z, c.w);
        return un.s;
    };

    const int xr = t >> 3, xcc = t & 7, xc = xcc ^ (xr & 7);
    const long xsoff = (long)(m0 + xr) * DIM + xc * 8;
    long wboff[3]; int wdst[3];
#pragma unroll
    for (int j = 0; j < 3; ++j) {
        const int idx = j * 512 + t;
        const int r = idx >> 3, cc = idx & 7, c = cc ^ (r & 7);
        wboff[j] = (long)r * DIM + c * 8;     // r = 0..191 into stacked wb
        wdst[j]  = idx * 8;                   // u16 offset into Wl
    }

    const int am = strip * 16 + li;
    const int a0off = am * 64 + ((g       ^ (am & 7)) * 8);
    const int a1off = am * 64 + (((g | 4) ^ (am & 7)) * 8);
    int boff[12];
#pragma unroll
    for (int ns = 0; ns < 6; ++ns) {
        const int n = nhalf * 96 + ns * 16 + li;
        boff[2*ns]   = n * 64 + ((g       ^ (n & 7)) * 8);
        boff[2*ns+1] = n * 64 + (((g | 4) ^ (n & 7)) * 8);
    }

    f32x4 acc[6];
#pragma unroll
    for (int i = 0; i < 6; ++i) acc[i] = (f32x4){0.f, 0.f, 0.f, 0.f};

    short8 xs  = ldbf(x, xsoff);
    short8 ws0 = *reinterpret_cast<const short8*>(wb + wboff[0]);
    short8 ws1 = *reinterpret_cast<const short8*>(wb + wboff[1]);
    short8 ws2 = *reinterpret_cast<const short8*>(wb + wboff[2]);

    for (int kc = 0; kc < 12; ++kc) {
        __syncthreads();                 // previous K-step's LDS reads done
        *reinterpret_cast<short8*>(&Xl[t * 8])    = xs;
        *reinterpret_cast<short8*>(&Wl[wdst[0]])  = ws0;
        *reinterpret_cast<short8*>(&Wl[wdst[1]])  = ws1;
        *reinterpret_cast<short8*>(&Wl[wdst[2]])  = ws2;
        if (kc < 11) {                   // prefetch next staging tile
            const long o = (long)(kc + 1) * 64;
            xs  = ldbf(x, xsoff + o);
            ws0 = *reinterpret_cast<const short8*>(wb + wboff[0] + o);
            ws1 = *reinterpret_cast<const short8*>(wb + wboff[1] + o);
            ws2 = *reinterpret_cast<const short8*>(wb + wboff[2] + o);
        }
        __syncthreads();                 // staging visible
        short8 af0 = *reinterpret_cast<const short8*>(&Xl[a0off]);
        short8 af1 = *reinterpret_cast<const short8*>(&Xl[a1off]);
#pragma unroll
        for (int ns = 0; ns < 6; ++ns) {
            short8 b0 = *reinterpret_cast<const short8*>(&Wl[boff[2*ns]]);
            short8 b1 = *reinterpret_cast<const short8*>(&Wl[boff[2*ns+1]]);
            acc[ns] = __builtin_amdgcn_mfma_f32_16x16x32_bf16(af0, b0, acc[ns], 0, 0, 0);
            acc[ns] = __builtin_amdgcn_mfma_f32_16x16x32_bf16(af1, b1, acc[ns], 0, 0, 0);
        }
    }

    // epilogue: q row-major; K fragment-major tile layout; V via LDS transpose
#pragma unroll
    for (int ns = 0; ns < 6; ++ns) {
        const int n = nhalf * 96 + ns * 16 + li;
#pragma unroll
        for (int r = 0; r < 4; ++r) {
            const int rowl = strip * 16 + g4 + r;
            u16 bv = f2bf(acc[ns][r]);
            if (n < 64) {
                qws[(long)(m0 + rowl) * HD + n] = bv;
            } else if (n < 128) {
                const int col = n - 64;                  // 0..63
                const int j   = 2 * strip + (col >> 5);  // m index
                const int gg  = (col >> 3) & 3;
                const int e   = col & 7;
                kws[(long)blockIdx.x * 4096 + j * 512 + (gg * 16 + (g4 + r)) * 8 + e] = bv;
            } else {
                Vt[rowl][n - 128] = bv;
            }
        }
    }
    __syncthreads();
    // V out in fragment-major layout: thread (d, mg) holds 8 consecutive kk
    // = mg*8..mg*8+7 for dim d -> contiguous short8 at (m, l) slot.
    {
        const int d  = t >> 3;   // 0..63
        const int mg = t & 7;    // 0..7
        union { u16 h[8]; short8 s; } u;
#pragma unroll
        for (int i = 0; i < 8; ++i) u.h[i] = Vt[mg * 8 + i][d];
        const int m  = 2 * (d >> 4) + (mg >> 2);
        const int lq = (mg & 3) * 16 + (d & 15);
        u16* dst = vpws + (long)blockIdx.x * 4096 + m * 512 + lq * 8;
        *reinterpret_cast<short8*>(dst) = u.s;
    }
}

// ---------------- Flash attention: 64 q-rows per wave, coalesced K/V ------
// Best-measured configuration (139.7us total, r8 bench): 64 q-rows/wave,
// 4-wave convoy, single Ps buffer, single-ka pipeline, heavy-first <=8-k-tile
// chunks (288 blocks), XCD-affine, fragment-major K/V loads (8 coalesced 1KB
// loads per tile). r10's uniform-4-tile/544-block variant REGRESSED (+3us
// attn, +37MB partial traffic): per-chunk fixed overhead (Q reload, double
// epilogue) outweighs the occupancy gain. Do not re-split.
__global__ __launch_bounds__(256, 2) void attn_kernel(
    const u32* __restrict__ xs,
    const u16* __restrict__ qw, const u16* __restrict__ kw,
    const u16* __restrict__ vpw, const u32* __restrict__ maskbits,
    char* __restrict__ part, void* __restrict__ out)
{
    __shared__ __align__(16) u16 Ps[4][4][16][72];   // 36.9 KB, per-wave regions

    const int flag = sniff_bf16(xs);
    const int t  = threadIdx.x;
    const int l  = t & 63;
    const int w  = t >> 6;
    const int li = l & 15;
    const int g  = l >> 4;
    const int g4 = g * 4;

    // XCD-affine decode: b = (bid%8)>>1; s = per-batch task 0..71, heavy first.
    const int bid = blockIdx.x;          // grid = 288
    const int b   = (bid & 7) >> 1;
    const int s   = (bid >> 3) * 2 + (bid & 1);
    int qt256, c;
    if      (s < 16) { qt256 = 15 - (s >> 3);              c = s & 7;  }  // 8 chunks
    else if (s < 30) { const int u = s - 16; qt256 = 13 - u / 7; c = u % 7; }
    else if (s < 42) { const int u = s - 30; qt256 = 11 - u / 6; c = u % 6; }
    else if (s < 52) { const int u = s - 42; qt256 = 9  - u / 5; c = u % 5; }
    else if (s < 60) { const int u = s - 52; qt256 = 7  - (u >> 2); c = u & 3; }
    else if (s < 66) { const int u = s - 60; qt256 = 5  - u / 3; c = u % 3; }
    else if (s < 70) { const int u = s - 66; qt256 = 3  - (u >> 1); c = u & 1; }
    else             { qt256 = 1 - (s - 70);               c = 0;  }      // 1 chunk
    const int nkt    = 4 * qt256 + 4;
    const int ktBeg  = c * 8;
    const int ktEnd  = min(ktBeg + 8, nkt);
    const int ntile  = ktEnd - ktBeg;            // 4..8, uniform across waves
    const bool single = (qt256 < 2);             // 1 chunk -> direct out write
    const int q0     = qt256 * 256 + w * 64;     // this wave's 64 q rows

    const u16* qrow = qw + ((long)(b * SEQ + q0 + li)) * HD + g * 8;
    short8 qf0 = *reinterpret_cast<const short8*>(qrow);
    short8 qf1 = *reinterpret_cast<const short8*>(qrow + 32);
    short8 qf2 = *reinterpret_cast<const short8*>(qrow + 16 * HD);
    short8 qf3 = *reinterpret_cast<const short8*>(qrow + 16 * HD + 32);
    short8 qf4 = *reinterpret_cast<const short8*>(qrow + 32 * HD);
    short8 qf5 = *reinterpret_cast<const short8*>(qrow + 32 * HD + 32);
    short8 qf6 = *reinterpret_cast<const short8*>(qrow + 48 * HD);
    short8 qf7 = *reinterpret_cast<const short8*>(qrow + 48 * HD + 32);

    short8 ones;
#pragma unroll
    for (int i = 0; i < 8; ++i) ones[i] = (short)0x3F80;  // bf16 1.0

    f32x4 O[16];
#pragma unroll
    for (int i = 0; i < 16; ++i) O[i] = (f32x4){0.f, 0.f, 0.f, 0.f};
    f32x4 l4A = (f32x4){0.f, 0.f, 0.f, 0.f};
    f32x4 l4B = (f32x4){0.f, 0.f, 0.f, 0.f};
    f32x4 l4C = (f32x4){0.f, 0.f, 0.f, 0.f};
    f32x4 l4D = (f32x4){0.f, 0.f, 0.f, 0.f};
    const int qgA = q0 + li;
    const int qgB = q0 + 16 + li;
    const int qgC = q0 + 32 + li;
    const int qgD = q0 + 48 + li;
    const f32x4 z4 = (f32x4){0.f, 0.f, 0.f, 0.f};

    // fragment-major tile bases: + l*8 makes every load lane-linear (16B/lane)
    const u16* kbase = kw  + (long)(b * 64) * 4096 + l * 8;
    const u16* vbase = vpw + (long)(b * 64) * 4096 + l * 8;
    const int tLast = ntile - 1;

    short8 ka[8];
    short8 vf[8];
    auto kload = [&](int i) {                     // clamped prefetch, tile idx
        const int tt = (i > tLast) ? tLast : i;
        const u16* kp = kbase + (long)(ktBeg + tt) * 4096;
#pragma unroll
        for (int m = 0; m < 8; ++m)
            ka[m] = *reinterpret_cast<const short8*>(kp + m * 512);
    };
    auto vfload = [&](int i) {
        const u16* vr = vbase + (long)(ktBeg + i) * 4096;
#pragma unroll
        for (int m = 0; m < 8; ++m)
            vf[m] = *reinterpret_cast<const short8*>(vr + m * 512);
    };
    auto sphase = [&](int i) {            // S^T + softmax -> Ps[w][qs], 4 subtiles
        const int k0 = (ktBeg + i) * 64;
        const u32 mb0 = maskbits[b * 128 + (k0 >> 5)];
        const u32 mb1 = maskbits[b * 128 + (k0 >> 5) + 1];
#pragma unroll
        for (int sub = 0; sub < 4; ++sub) {
            const u32 word = (sub & 2) ? mb1 : mb0;
            const int klb = k0 + sub * 16 + g4;
            const int sh  = (sub & 1) * 16 + g4;
            // subtile A
            {
                f32x4 a = __builtin_amdgcn_mfma_f32_16x16x32_bf16(ka[2*sub],   qf0, z4, 0, 0, 0);
                a       = __builtin_amdgcn_mfma_f32_16x16x32_bf16(ka[2*sub+1], qf1, a,  0, 0, 0);
                float p[4];
#pragma unroll
                for (int r = 0; r < 4; ++r) {
                    const bool keep = ((klb + r) <= qgA) && (((word >> (sh + r)) & 1u) != 0u);
                    p[r] = ex2(fmaf(a[r], SSCALE, keep ? CSHIFT : NEGBIG));
                }
                *reinterpret_cast<uint2*>(&Ps[w][0][li][sub * 16 + g4]) =
                    make_uint2(pkbf(p[0], p[1]), pkbf(p[2], p[3]));
            }
            // subtile B
            {
                f32x4 a = __builtin_amdgcn_mfma_f32_16x16x32_bf16(ka[2*sub],   qf2, z4, 0, 0, 0);
                a       = __builtin_amdgcn_mfma_f32_16x16x32_bf16(ka[2*sub+1], qf3, a,  0, 0, 0);
                float p[4];
#pragma unroll
                for (int r = 0; r < 4; ++r) {
                    const bool keep = ((klb + r) <= qgB) && (((word >> (sh + r)) & 1u) != 0u);
                    p[r] = ex2(fmaf(a[r], SSCALE, keep ? CSHIFT : NEGBIG));
                }
                *reinterpret_cast<uint2*>(&Ps[w][1][li][sub * 16 + g4]) =
                    make_uint2(pkbf(p[0], p[1]), pkbf(p[2], p[3]));
            }
            // subtile C
            {
                f32x4 a = __builtin_amdgcn_mfma_f32_16x16x32_bf16(ka[2*sub],   qf4, z4, 0, 0, 0);
                a       = __builtin_amdgcn_mfma_f32_16x16x32_bf16(ka[2*sub+1], qf5, a,  0, 0, 0);
                float p[4];
#pragma unroll
                for (int r = 0; r < 4; ++r) {
                    const bool keep = ((klb + r) <= qgC) && (((word >> (sh + r)) & 1u) != 0u);
                    p[r] = ex2(fmaf(a[r], SSCALE, keep ? CSHIFT : NEGBIG));
                }
                *reinterpret_cast<uint2*>(&Ps[w][2][li][sub * 16 + g4]) =
                    make_uint2(pkbf(p[0], p[1]), pkbf(p[2], p[3]));
            }
            // subtile D
            {
                f32x4 a = __builtin_amdgcn_mfma_f32_16x16x32_bf16(ka[2*sub],   qf6, z4, 0, 0, 0);
                a       = __builtin_amdgcn_mfma_f32_16x16x32_bf16(ka[2*sub+1], qf7, a,  0, 0, 0);
                float p[4];
#pragma unroll
                for (int r = 0; r < 4; ++r) {
                    const bool keep = ((klb + r) <= qgD) && (((word >> (sh + r)) & 1u) != 0u);
                    p[r] = ex2(fmaf(a[r], SSCALE, keep ? CSHIFT : NEGBIG));
                }
                *reinterpret_cast<uint2*>(&Ps[w][3][li][sub * 16 + g4]) =
                    make_uint2(pkbf(p[0], p[1]), pkbf(p[2], p[3]));
            }
        }
    };

    kload(0);
    sphase(0);
    kload(1);
    for (int i = 0; i < ntile; ++i) {
        __builtin_amdgcn_s_barrier();   // convoy: keep 4 waves on same tile
        vfload(i);
        short8 A1A = *reinterpret_cast<const short8*>(&Ps[w][0][li][g * 8]);
        short8 A2A = *reinterpret_cast<const short8*>(&Ps[w][0][li][32 + g * 8]);
        short8 A1B = *reinterpret_cast<const short8*>(&Ps[w][1][li][g * 8]);
        short8 A2B = *reinterpret_cast<const short8*>(&Ps[w][1][li][32 + g * 8]);
        short8 A1C = *reinterpret_cast<const short8*>(&Ps[w][2][li][g * 8]);
        short8 A2C = *reinterpret_cast<const short8*>(&Ps[w][2][li][32 + g * 8]);
        short8 A1D = *reinterpret_cast<const short8*>(&Ps[w][3][li][g * 8]);
        short8 A2D = *reinterpret_cast<const short8*>(&Ps[w][3][li][32 + g * 8]);
        if (i + 1 < ntile) {
            sphase(i + 1);               // overwrites Ps AFTER the reg-reads above
            kload(i + 2);                // refill single K buffer (clamped)
        }
        f32x4 lt;
        lt = __builtin_amdgcn_mfma_f32_16x16x32_bf16(A1A, ones, z4, 0, 0, 0);
        lt = __builtin_amdgcn_mfma_f32_16x16x32_bf16(A2A, ones, lt, 0, 0, 0);
#pragma unroll
        for (int r = 0; r < 4; ++r) l4A[r] += lt[r];
        lt = __builtin_amdgcn_mfma_f32_16x16x32_bf16(A1B, ones, z4, 0, 0, 0);
        lt = __builtin_amdgcn_mfma_f32_16x16x32_bf16(A2B, ones, lt, 0, 0, 0);
#pragma unroll
        for (int r = 0; r < 4; ++r) l4B[r] += lt[r];
        lt = __builtin_amdgcn_mfma_f32_16x16x32_bf16(A1C, ones, z4, 0, 0, 0);
        lt = __builtin_amdgcn_mfma_f32_16x16x32_bf16(A2C, ones, lt, 0, 0, 0);
#pragma unroll
        for (int r = 0; r < 4; ++r) l4C[r] += lt[r];
        lt = __builtin_amdgcn_mfma_f32_16x16x32_bf16(A1D, ones, z4, 0, 0, 0);
        lt = __builtin_amdgcn_mfma_f32_16x16x32_bf16(A2D, ones, lt, 0, 0, 0);
#pragma unroll
        for (int r = 0; r < 4; ++r) l4D[r] += lt[r];
#pragma unroll
        for (int ds = 0; ds < 4; ++ds) {
            O[ds]      = __builtin_amdgcn_mfma_f32_16x16x32_bf16(A1A, vf[2*ds],   O[ds],      0, 0, 0);
            O[ds]      = __builtin_amdgcn_mfma_f32_16x16x32_bf16(A2A, vf[2*ds+1], O[ds],      0, 0, 0);
            O[4 + ds]  = __builtin_amdgcn_mfma_f32_16x16x32_bf16(A1B, vf[2*ds],   O[4 + ds],  0, 0, 0);
            O[4 + ds]  = __builtin_amdgcn_mfma_f32_16x16x32_bf16(A2B, vf[2*ds+1], O[4 + ds],  0, 0, 0);
            O[8 + ds]  = __builtin_amdgcn_mfma_f32_16x16x32_bf16(A1C, vf[2*ds],   O[8 + ds],  0, 0, 0);
            O[8 + ds]  = __builtin_amdgcn_mfma_f32_16x16x32_bf16(A2C, vf[2*ds+1], O[8 + ds],  0, 0, 0);
            O[12 + ds] = __builtin_amdgcn_mfma_f32_16x16x32_bf16(A1D, vf[2*ds],   O[12 + ds], 0, 0, 0);
            O[12 + ds] = __builtin_amdgcn_mfma_f32_16x16x32_bf16(A2D, vf[2*ds+1], O[12 + ds], 0, 0, 0);
        }
    }

    // ---- per-wave epilogue: two 32-row passes through this wave's Ps region ----
    {
        float* Of = reinterpret_cast<float*>(&Ps[w][0][0][0]);
        float* Lf = Of + 2112;
        const int r32 = l >> 1;          // 0..31: output row within pass
        const int h   = l & 1;           // column half (32 cols)
#pragma unroll
        for (int p = 0; p < 2; ++p) {
#pragma unroll
            for (int tile = 0; tile < 2; ++tile)
#pragma unroll
                for (int ds = 0; ds < 4; ++ds)
#pragma unroll
                    for (int r = 0; r < 4; ++r)
                        Of[(tile * 16 + g4 + r) * 66 + ds * 16 + li] =
                            O[(p * 2 + tile) * 4 + ds][r];
            if (li == 0) {
#pragma unroll
                for (int r = 0; r < 4; ++r) {
                    Lf[g4 + r]      = p ? l4C[r] : l4A[r];
                    Lf[16 + g4 + r] = p ? l4D[r] : l4B[r];
                }
            }
            float v[32];
#pragma unroll
            for (int j = 0; j < 8; ++j) {
                float4 f = *reinterpret_cast<const float4*>(&Of[r32 * 66 + h * 32 + j * 4]);
                v[4*j] = f.x; v[4*j+1] = f.y; v[4*j+2] = f.z; v[4*j+3] = f.w;
            }
            if (single) {
                const float L = Lf[r32];
                const float rl = (L > 0.f) ? 1.f / L : 0.f;
#pragma unroll
                for (int j = 0; j < 32; ++j) v[j] *= rl;
                const long row = (long)(b * SEQ + q0 + p * 32 + r32);
                if (flag) {
                    u16* dst = (u16*)out + row * HD + h * 32;
#pragma unroll
                    for (int jj = 0; jj < 4; ++jj) {
                        uint4 st = make_uint4(pkbf(v[8*jj],   v[8*jj+1]), pkbf(v[8*jj+2], v[8*jj+3]),
                                              pkbf(v[8*jj+4], v[8*jj+5]), pkbf(v[8*jj+6], v[8*jj+7]));
                        *reinterpret_cast<uint4*>(dst + jj * 8) = st;
                    }
                } else {
                    float* dst = (float*)out + row * HD + h * 32;
#pragma unroll
                    for (int jj = 0; jj < 8; ++jj)
                        *reinterpret_cast<float4*>(dst + jj * 4) =
                            make_float4(v[4*jj], v[4*jj+1], v[4*jj+2], v[4*jj+3]);
                }
            } else {
                const int slotIdx = ((b * 72 + chunk_off(qt256) + c) * 8 + w * 2 + p);
                char* slot = part + (long)slotIdx * PSLOTB;
                u16* dst = (u16*)slot + r32 * 64 + h * 32;
#pragma unroll
                for (int jj = 0; jj < 4; ++jj) {
                    uint4 st = make_uint4(pkbf(v[8*jj],   v[8*jj+1]), pkbf(v[8*jj+2], v[8*jj+3]),
                                          pkbf(v[8*jj+4], v[8*jj+5]), pkbf(v[8*jj+6], v[8*jj+7]));
                    *reinterpret_cast<uint4*>(dst + jj * 8) = st;
                }
                if (l < 32)
                    *reinterpret_cast<float*>(slot + 4096 + l * 4) = Lf[l];
            }
        }
    }
}

// ---------------- merge split-K partials (qt256 >= 2): plain sum ----------
__global__ __launch_bounds__(256) void merge_kernel(
    const u32* __restrict__ xs, const char* __restrict__ part,
    void* __restrict__ out)
{
    const int flag = sniff_bf16(xs);
    const int bid = blockIdx.x;         // 448
    const int b = bid & 3;
    const int u = bid >> 2;             // 0..111
    const int qt256 = 2 + u / 8;        // 2..15
    const int v8 = u % 8;
    const int w = v8 >> 1;              // wave 0..3
    const int p = v8 & 1;               // half-pass 0..1
    const int nc = (qt256 >> 1) + 1;    // 2..8 chunks
    const int t  = threadIdx.x;
    const int qq = t >> 3;              // 0..31
    const int dd = (t & 7) * 8;         // 0..56
    const char* s0 = part +
        ((long)((b * 72 + chunk_off(qt256)) * 8 + w * 2 + p)) * PSLOTB;
    float L = 0.f;
    float a8[8];
#pragma unroll
    for (int j = 0; j < 8; ++j) a8[j] = 0.f;
    for (int c = 0; c < nc; ++c) {
        const char* sc = s0 + (long)c * 8 * PSLOTB;   // c-stride = 8 slots
        L += *reinterpret_cast<const float*>(sc + 4096 + qq * 4);
        ushort4 x0 = *reinterpret_cast<const ushort4*>((const u16*)sc + qq * 64 + dd);
        ushort4 x1 = *reinterpret_cast<const ushort4*>((const u16*)sc + qq * 64 + dd + 4);
        a8[0] += bfbits2f(x0.x); a8[1] += bfbits2f(x0.y);
        a8[2] += bfbits2f(x0.z); a8[3] += bfbits2f(x0.w);
        a8[4] += bfbits2f(x1.x); a8[5] += bfbits2f(x1.y);
        a8[6] += bfbits2f(x1.z); a8[7] += bfbits2f(x1.w);
    }
    const float rl = (L > 0.f) ? 1.f / L : 0.f;
#pragma unroll
    for (int j = 0; j < 8; ++j) a8[j] *= rl;
    const long row = (long)(b * SEQ + qt256 * 256 + w * 64 + p * 32 + qq);
    if (flag) {
        uint4 st = make_uint4(pkbf(a8[0], a8[1]), pkbf(a8[2], a8[3]),
                              pkbf(a8[4], a8[5]), pkbf(a8[6], a8[7]));
        *reinterpret_cast<uint4*>((u16*)out + row * HD + dd) = st;
    } else {
        *reinterpret_cast<float4*>((float*)out + row * HD + dd) =
            make_float4(a8[0], a8[1], a8[2], a8[3]);
        *reinterpret_cast<float4*>((float*)out + row * HD + dd + 4) =
            make_float4(a8[4], a8[5], a8[6], a8[7]);
    }
}

extern "C" void kernel_launch(void* const* d_in, const int* in_sizes, int n_in,
                              void* d_out, int out_size, void* d_ws, size_t ws_size,
                              hipStream_t stream) {
    const void* x   = d_in[0];
    const int* mask = (const int*)d_in[1];
    const void* wq  = d_in[2];
    const void* wk  = d_in[3];
    const void* wv  = d_in[4];
    const u32* xs   = (const u32*)x;

    u16* q    = (u16*)d_ws;                          // 2 MB
    u16* k    = q  + (long)NROW * HD;                // 2 MB (fragment-major tiles)
    u16* vp   = k  + (long)NROW * HD;                // 2 MB (fragment-major tiles)
    u32* mb   = (u32*)(vp + (long)NROW * HD);        // 2 KB
    char* part = (char*)(mb + 512);                  // 2304 slots = 9.73 MB
    u16* wb   = (u16*)(part + (long)NSLOT * PSLOTB); // 288 KB bf16 W

    wconv_kernel<<<72, 256, 0, stream>>>(xs, wq, wk, wv, wb);
    qkv_kernel  <<<258, 512, 0, stream>>>(x, wb, mask, q, k, vp, mb);
    attn_kernel <<<288, 256, 0, stream>>>(xs, q, k, vp, mb, part, d_out);
    merge_kernel<<<448, 256, 0, stream>>>(xs, part, d_out);
}

// Round 12
// 139.871 us; speedup vs baseline: 1.0935x; 1.0037x over previous
//
#include <hip/hip_runtime.h>
#include <hip/hip_bf16.h>

typedef unsigned int u32;
typedef unsigned short u16;
typedef unsigned long long u64;
typedef __attribute__((ext_vector_type(8))) short short8;
typedef __attribute__((ext_vector_type(4))) float f32x4;

#define BATCH 4
#define SEQ   4096
#define DIM   768
#define HD    64
#define NROW  (BATCH*SEQ)   // 16384
#define LOG2E 1.44269504088896f
#define SSCALE (0.125f * LOG2E)
#define CSHIFT (-32.0f)      // fixed exp2-domain shift (softmax shift-invariant)
#define NEGBIG (-1.0e30f)
#define PSLOTB 4224          // partial slot: 4096 B bf16 O[32][64] + 128 B f32 l[32]
#define NSLOT  2304          // 4 batches x 72 chunk-slots x 8 (wave,halfpass)

__device__ __forceinline__ float ex2(float x) { return __builtin_amdgcn_exp2f(x); }
__device__ __forceinline__ float bfbits2f(u16 u) {
    return __uint_as_float(((u32)u) << 16);
}
__device__ __forceinline__ u16 f2bf(float f) {
    return (u16)((__float_as_uint(f) + 0x8000u) >> 16);
}
__device__ __forceinline__ u32 pkbf(float a, float b) { // lo16=bf(a), hi16=bf(b)
    u32 xa = __float_as_uint(a) + 0x8000u;
    u32 xb = __float_as_uint(b) + 0x8000u;
    return __builtin_amdgcn_perm(xb, xa, 0x07060302);
}
// Deterministic per-wave dtype sniff (same answer in every wave/block).
__device__ __forceinline__ int sniff_bf16(const u32* x) {
    u32 w = x[threadIdx.x & 63];
    u32 lo = w & 0xffffu;
    u32 e  = (lo >> 7) & 0xffu;
    bool ok = (lo == 0u) || (e >= 96u && e <= 134u);
    u64 bal = __ballot(ok);
    return (__popcll(bal) >= 48) ? 1 : 0;
}
// chunk-slot prefix for qt256 (256-row q tiles, chunks of 8 k-tiles):
// nchunk(j) = (j>>1)+1; off(n) = h*(h-1+(n&1)) + n, h=n>>1. Total 72/batch.
__device__ __forceinline__ int chunk_off(int n) {
    const int h = n >> 1;
    return h * (h - 1 + (n & 1)) + n;
}

// ---------------- W pre-conversion: fp32 -> bf16, ONCE ---------------------
__global__ __launch_bounds__(256) void wconv_kernel(
    const u32* __restrict__ xs,
    const void* __restrict__ wq, const void* __restrict__ wk,
    const void* __restrict__ wv, u16* __restrict__ wb)
{
    const int flag = sniff_bf16(xs);
    const int j = blockIdx.x * 256 + threadIdx.x;   // 0..18431
    const int e = j * 8;
    const int r = e / DIM;          // 0..191  ([wq;wk;wv] stacked)
    const int c = e - r * DIM;
    const void* src = (r < 64) ? wq : (r < 128) ? wk : wv;
    const long soff = (long)(r & 63) * DIM + c;
    if (flag) {
        *reinterpret_cast<short8*>(wb + (long)r * DIM + c) =
            *reinterpret_cast<const short8*>((const u16*)src + soff);
    } else {
        const float* p = (const float*)src + soff;
        float4 a = *reinterpret_cast<const float4*>(p);
        float4 d = *reinterpret_cast<const float4*>(p + 4);
        union { u32 u[4]; short8 s; } un;
        un.u[0] = pkbf(a.x, a.y); un.u[1] = pkbf(a.z, a.w);
        un.u[2] = pkbf(d.x, d.y); un.u[3] = pkbf(d.z, d.w);
        *reinterpret_cast<short8*>(wb + (long)r * DIM + c) = un.s;
    }
}

// ---------------- QKV projection: LDS-tiled GEMM, double-buffered -----------
// K and V written in MFMA-FRAGMENT-MAJOR tile layout (harness-verified r8):
//   element (m, lane l, elem e) at tile*4096 + m*512 + l*8 + e (u16)
//   K: row=16s+(l&15), col=32h+8*(l>>4)+e, m=2s+h
//   V: dim d=16*(m>>1)+(l&15), seqpos kk=32*(m&1)+8*(l>>4)+e
// r11 change: DOUBLE-BUFFERED X/W LDS -> ONE barrier per K-step (was 2).
// At 258 blocks (~1/CU) there is no co-resident block to hide barrier
// drains; 12 of the 24 per-block drains are pure WAR protection that the
// dbuf eliminates. Safety: step-kc reads of buf[kc&1] complete before
// barrier(kc+1), which precedes the step-kc+2 overwrite of that buffer.
// LDS 72.4 KB (< 160 KB workgroup limit; 1 block/CU unaffected).
// NOTE (r10): splitting into half-column blocks REGRESSED (+5us) — keep
// monolithic 258-block form.
__global__ __launch_bounds__(512, 4) void qkv_kernel(
    const void* __restrict__ x, const u16* __restrict__ wb,
    const int* __restrict__ mask,
    u16* __restrict__ qws, u16* __restrict__ kws, u16* __restrict__ vpws,
    u32* __restrict__ mb)
{
    const int t = threadIdx.x;
    const int l = t & 63;
    const int w = t >> 6;

    if (blockIdx.x >= 256) {            // ---- mask bit-pack ----
        const int base = (blockIdx.x - 256) * 8192 + w * 1024;
#pragma unroll
        for (int it = 0; it < 16; ++it) {
            const int idx = base + it * 64 + l;
            u64 bal = __ballot(mask[idx] != 0);
            if (l == 0)       mb[idx >> 5] = (u32)bal;
            else if (l == 32) mb[idx >> 5] = (u32)(bal >> 32);
        }
        return;
    }

    const int flag = sniff_bf16((const u32*)x);
    __shared__ __align__(16) u16 Xl[2][64 * 64];    // 16 KB (double-buffered)
    __shared__ __align__(16) u16 Wl[2][192 * 64];   // 48 KB (double-buffered)
    __shared__ u16 Vt[64][66];                      // 8.4 KB transpose staging

    const int li = l & 15;
    const int g  = l >> 4;
    const int g4 = g * 4;
    const int strip = w & 3;            // 16-row strip
    const int nhalf = w >> 2;           // 96-col half
    const int m0 = blockIdx.x * 64;
    const int b  = m0 >> 12;

    auto ldbf = [&](const void* bp, long off) -> short8 {
        if (flag) return *reinterpret_cast<const short8*>((const u16*)bp + off);
        const float* p = (const float*)bp + off;
        float4 a = *reinterpret_cast<const float4*>(p);
        float4 c = *reinterpret_cast<const float4*>(p + 4);
        union { u32 u[4]; short8 s; } un;
        un.u[0] = pkbf(a.x, a.y); un.u[1] = pkbf(a.z, a.w);
        un.u[2] = pkbf(c.x, c.y); un.u[3] = pkbf(c.z, c.w);
        return un.s;
    };

    const int xr = t >> 3, xcc = t & 7, xc = xcc ^ (xr & 7);
    const long xsoff = (long)(m0 + xr) * DIM + xc * 8;
    long wboff[3]; int wdst[3];
#pragma unroll
    for (int j = 0; j < 3; ++j) {
        const int idx = j * 512 + t;
        const int r = idx >> 3, cc = idx & 7, c = cc ^ (r & 7);
        wboff[j] = (long)r * DIM + c * 8;     // r = 0..191 into stacked wb
        wdst[j]  = idx * 8;                   // u16 offset into Wl
    }

    const int am = strip * 16 + li;
    const int a0off = am * 64 + ((g       ^ (am & 7)) * 8);
    const int a1off = am * 64 + (((g | 4) ^ (am & 7)) * 8);
    int boff[12];
#pragma unroll
    for (int ns = 0; ns < 6; ++ns) {
        const int n = nhalf * 96 + ns * 16 + li;
        boff[2*ns]   = n * 64 + ((g       ^ (n & 7)) * 8);
        boff[2*ns+1] = n * 64 + (((g | 4) ^ (n & 7)) * 8);
    }

    f32x4 acc[6];
#pragma unroll
    for (int i = 0; i < 6; ++i) acc[i] = (f32x4){0.f, 0.f, 0.f, 0.f};

    short8 xs  = ldbf(x, xsoff);
    short8 ws0 = *reinterpret_cast<const short8*>(wb + wboff[0]);
    short8 ws1 = *reinterpret_cast<const short8*>(wb + wboff[1]);
    short8 ws2 = *reinterpret_cast<const short8*>(wb + wboff[2]);

    for (int kc = 0; kc < 12; ++kc) {
        u16* Xc = &Xl[kc & 1][0];
        u16* Wc = &Wl[kc & 1][0];
        *reinterpret_cast<short8*>(&Xc[t * 8])    = xs;
        *reinterpret_cast<short8*>(&Wc[wdst[0]])  = ws0;
        *reinterpret_cast<short8*>(&Wc[wdst[1]])  = ws1;
        *reinterpret_cast<short8*>(&Wc[wdst[2]])  = ws2;
        if (kc < 11) {                   // prefetch next staging tile
            const long o = (long)(kc + 1) * 64;
            xs  = ldbf(x, xsoff + o);
            ws0 = *reinterpret_cast<const short8*>(wb + wboff[0] + o);
            ws1 = *reinterpret_cast<const short8*>(wb + wboff[1] + o);
            ws2 = *reinterpret_cast<const short8*>(wb + wboff[2] + o);
        }
        __syncthreads();                 // single barrier: staging visible
        short8 af0 = *reinterpret_cast<const short8*>(&Xc[a0off]);
        short8 af1 = *reinterpret_cast<const short8*>(&Xc[a1off]);
#pragma unroll
        for (int ns = 0; ns < 6; ++ns) {
            short8 b0 = *reinterpret_cast<const short8*>(&Wc[boff[2*ns]]);
            short8 b1 = *reinterpret_cast<const short8*>(&Wc[boff[2*ns+1]]);
            acc[ns] = __builtin_amdgcn_mfma_f32_16x16x32_bf16(af0, b0, acc[ns], 0, 0, 0);
            acc[ns] = __builtin_amdgcn_mfma_f32_16x16x32_bf16(af1, b1, acc[ns], 0, 0, 0);
        }
    }

    // epilogue: q row-major; K fragment-major tile layout; V via LDS transpose
#pragma unroll
    for (int ns = 0; ns < 6; ++ns) {
        const int n = nhalf * 96 + ns * 16 + li;
#pragma unroll
        for (int r = 0; r < 4; ++r) {
            const int rowl = strip * 16 + g4 + r;
            u16 bv = f2bf(acc[ns][r]);
            if (n < 64) {
                qws[(long)(m0 + rowl) * HD + n] = bv;
            } else if (n < 128) {
                const int col = n - 64;                  // 0..63
                const int j   = 2 * strip + (col >> 5);  // m index
                const int gg  = (col >> 3) & 3;
                const int e   = col & 7;
                kws[(long)blockIdx.x * 4096 + j * 512 + (gg * 16 + (g4 + r)) * 8 + e] = bv;
            } else {
                Vt[rowl][n - 128] = bv;
            }
        }
    }
    __syncthreads();
    // V out in fragment-major layout: thread (d, mg) holds 8 consecutive kk
    // = mg*8..mg*8+7 for dim d -> contiguous short8 at (m, l) slot.
    {
        const int d  = t >> 3;   // 0..63
        const int mg = t & 7;    // 0..7
        union { u16 h[8]; short8 s; } u;
#pragma unroll
        for (int i = 0; i < 8; ++i) u.h[i] = Vt[mg * 8 + i][d];
        const int m  = 2 * (d >> 4) + (mg >> 2);
        const int lq = (mg & 3) * 16 + (d & 15);
        u16* dst = vpws + (long)blockIdx.x * 4096 + m * 512 + lq * 8;
        *reinterpret_cast<short8*>(dst) = u.s;
    }
}

// ---------------- Flash attention: 64 q-rows per wave, coalesced K/V ------
// Best-measured configuration (139.7/140.4us total, r8/r11 benches):
// 64 q-rows/wave, 4-wave convoy, single Ps buffer, single-ka pipeline,
// heavy-first <=8-k-tile chunks (288 blocks), XCD-affine, fragment-major
// K/V loads (8 coalesced 1KB loads per tile). r10's uniform-4-tile/544-block
// variant REGRESSED (+3us attn, +37MB partial traffic). Do not re-split.
__global__ __launch_bounds__(256, 2) void attn_kernel(
    const u32* __restrict__ xs,
    const u16* __restrict__ qw, const u16* __restrict__ kw,
    const u16* __restrict__ vpw, const u32* __restrict__ maskbits,
    char* __restrict__ part, void* __restrict__ out)
{
    __shared__ __align__(16) u16 Ps[4][4][16][72];   // 36.9 KB, per-wave regions

    const int flag = sniff_bf16(xs);
    const int t  = threadIdx.x;
    const int l  = t & 63;
    const int w  = t >> 6;
    const int li = l & 15;
    const int g  = l >> 4;
    const int g4 = g * 4;

    // XCD-affine decode: b = (bid%8)>>1; s = per-batch task 0..71, heavy first.
    const int bid = blockIdx.x;          // grid = 288
    const int b   = (bid & 7) >> 1;
    const int s   = (bid >> 3) * 2 + (bid & 1);
    int qt256, c;
    if      (s < 16) { qt256 = 15 - (s >> 3);              c = s & 7;  }  // 8 chunks
    else if (s < 30) { const int u = s - 16; qt256 = 13 - u / 7; c = u % 7; }
    else if (s < 42) { const int u = s - 30; qt256 = 11 - u / 6; c = u % 6; }
    else if (s < 52) { const int u = s - 42; qt256 = 9  - u / 5; c = u % 5; }
    else if (s < 60) { const int u = s - 52; qt256 = 7  - (u >> 2); c = u & 3; }
    else if (s < 66) { const int u = s - 60; qt256 = 5  - u / 3; c = u % 3; }
    else if (s < 70) { const int u = s - 66; qt256 = 3  - (u >> 1); c = u & 1; }
    else             { qt256 = 1 - (s - 70);               c = 0;  }      // 1 chunk
    const int nkt    = 4 * qt256 + 4;
    const int ktBeg  = c * 8;
    const int ktEnd  = min(ktBeg + 8, nkt);
    const int ntile  = ktEnd - ktBeg;            // 4..8, uniform across waves
    const bool single = (qt256 < 2);             // 1 chunk -> direct out write
    const int q0     = qt256 * 256 + w * 64;     // this wave's 64 q rows

    const u16* qrow = qw + ((long)(b * SEQ + q0 + li)) * HD + g * 8;
    short8 qf0 = *reinterpret_cast<const short8*>(qrow);
    short8 qf1 = *reinterpret_cast<const short8*>(qrow + 32);
    short8 qf2 = *reinterpret_cast<const short8*>(qrow + 16 * HD);
    short8 qf3 = *reinterpret_cast<const short8*>(qrow + 16 * HD + 32);
    short8 qf4 = *reinterpret_cast<const short8*>(qrow + 32 * HD);
    short8 qf5 = *reinterpret_cast<const short8*>(qrow + 32 * HD + 32);
    short8 qf6 = *reinterpret_cast<const short8*>(qrow + 48 * HD);
    short8 qf7 = *reinterpret_cast<const short8*>(qrow + 48 * HD + 32);

    short8 ones;
#pragma unroll
    for (int i = 0; i < 8; ++i) ones[i] = (short)0x3F80;  // bf16 1.0

    f32x4 O[16];
#pragma unroll
    for (int i = 0; i < 16; ++i) O[i] = (f32x4){0.f, 0.f, 0.f, 0.f};
    f32x4 l4A = (f32x4){0.f, 0.f, 0.f, 0.f};
    f32x4 l4B = (f32x4){0.f, 0.f, 0.f, 0.f};
    f32x4 l4C = (f32x4){0.f, 0.f, 0.f, 0.f};
    f32x4 l4D = (f32x4){0.f, 0.f, 0.f, 0.f};
    const int qgA = q0 + li;
    const int qgB = q0 + 16 + li;
    const int qgC = q0 + 32 + li;
    const int qgD = q0 + 48 + li;
    const f32x4 z4 = (f32x4){0.f, 0.f, 0.f, 0.f};

    // fragment-major tile bases: + l*8 makes every load lane-linear (16B/lane)
    const u16* kbase = kw  + (long)(b * 64) * 4096 + l * 8;
    const u16* vbase = vpw + (long)(b * 64) * 4096 + l * 8;
    const int tLast = ntile - 1;

    short8 ka[8];
    short8 vf[8];
    auto kload = [&](int i) {                     // clamped prefetch, tile idx
        const int tt = (i > tLast) ? tLast : i;
        const u16* kp = kbase + (long)(ktBeg + tt) * 4096;
#pragma unroll
        for (int m = 0; m < 8; ++m)
            ka[m] = *reinterpret_cast<const short8*>(kp + m * 512);
    };
    auto vfload = [&](int i) {
        const u16* vr = vbase + (long)(ktBeg + i) * 4096;
#pragma unroll
        for (int m = 0; m < 8; ++m)
            vf[m] = *reinterpret_cast<const short8*>(vr + m * 512);
    };
    auto sphase = [&](int i) {            // S^T + softmax -> Ps[w][qs], 4 subtiles
        const int k0 = (ktBeg + i) * 64;
        const u32 mb0 = maskbits[b * 128 + (k0 >> 5)];
        const u32 mb1 = maskbits[b * 128 + (k0 >> 5) + 1];
#pragma unroll
        for (int sub = 0; sub < 4; ++sub) {
            const u32 word = (sub & 2) ? mb1 : mb0;
            const int klb = k0 + sub * 16 + g4;
            const int sh  = (sub & 1) * 16 + g4;
            // subtile A
            {
                f32x4 a = __builtin_amdgcn_mfma_f32_16x16x32_bf16(ka[2*sub],   qf0, z4, 0, 0, 0);
                a       = __builtin_amdgcn_mfma_f32_16x16x32_bf16(ka[2*sub+1], qf1, a,  0, 0, 0);
                float p[4];
#pragma unroll
                for (int r = 0; r < 4; ++r) {
                    const bool keep = ((klb + r) <= qgA) && (((word >> (sh + r)) & 1u) != 0u);
                    p[r] = ex2(fmaf(a[r], SSCALE, keep ? CSHIFT : NEGBIG));
                }
                *reinterpret_cast<uint2*>(&Ps[w][0][li][sub * 16 + g4]) =
                    make_uint2(pkbf(p[0], p[1]), pkbf(p[2], p[3]));
            }
            // subtile B
            {
                f32x4 a = __builtin_amdgcn_mfma_f32_16x16x32_bf16(ka[2*sub],   qf2, z4, 0, 0, 0);
                a       = __builtin_amdgcn_mfma_f32_16x16x32_bf16(ka[2*sub+1], qf3, a,  0, 0, 0);
                float p[4];
#pragma unroll
                for (int r = 0; r < 4; ++r) {
                    const bool keep = ((klb + r) <= qgB) && (((word >> (sh + r)) & 1u) != 0u);
                    p[r] = ex2(fmaf(a[r], SSCALE, keep ? CSHIFT : NEGBIG));
                }
                *reinterpret_cast<uint2*>(&Ps[w][1][li][sub * 16 + g4]) =
                    make_uint2(pkbf(p[0], p[1]), pkbf(p[2], p[3]));
            }
            // subtile C
            {
                f32x4 a = __builtin_amdgcn_mfma_f32_16x16x32_bf16(ka[2*sub],   qf4, z4, 0, 0, 0);
                a       = __builtin_amdgcn_mfma_f32_16x16x32_bf16(ka[2*sub+1], qf5, a,  0, 0, 0);
                float p[4];
#pragma unroll
                for (int r = 0; r < 4; ++r) {
                    const bool keep = ((klb + r) <= qgC) && (((word >> (sh + r)) & 1u) != 0u);
                    p[r] = ex2(fmaf(a[r], SSCALE, keep ? CSHIFT : NEGBIG));
                }
                *reinterpret_cast<uint2*>(&Ps[w][2][li][sub * 16 + g4]) =
                    make_uint2(pkbf(p[0], p[1]), pkbf(p[2], p[3]));
            }
            // subtile D
            {
                f32x4 a = __builtin_amdgcn_mfma_f32_16x16x32_bf16(ka[2*sub],   qf6, z4, 0, 0, 0);
                a       = __builtin_amdgcn_mfma_f32_16x16x32_bf16(ka[2*sub+1], qf7, a,  0, 0, 0);
                float p[4];
#pragma unroll
                for (int r = 0; r < 4; ++r) {
                    const bool keep = ((klb + r) <= qgD) && (((word >> (sh + r)) & 1u) != 0u);
                    p[r] = ex2(fmaf(a[r], SSCALE, keep ? CSHIFT : NEGBIG));
                }
                *reinterpret_cast<uint2*>(&Ps[w][3][li][sub * 16 + g4]) =
                    make_uint2(pkbf(p[0], p[1]), pkbf(p[2], p[3]));
            }
        }
    };

    kload(0);
    sphase(0);
    kload(1);
    for (int i = 0; i < ntile; ++i) {
        __builtin_amdgcn_s_barrier();   // convoy: keep 4 waves on same tile
        vfload(i);
        short8 A1A = *reinterpret_cast<const short8*>(&Ps[w][0][li][g * 8]);
        short8 A2A = *reinterpret_cast<const short8*>(&Ps[w][0][li][32 + g * 8]);
        short8 A1B = *reinterpret_cast<const short8*>(&Ps[w][1][li][g * 8]);
        short8 A2B = *reinterpret_cast<const short8*>(&Ps[w][1][li][32 + g * 8]);
        short8 A1C = *reinterpret_cast<const short8*>(&Ps[w][2][li][g * 8]);
        short8 A2C = *reinterpret_cast<const short8*>(&Ps[w][2][li][32 + g * 8]);
        short8 A1D = *reinterpret_cast<const short8*>(&Ps[w][3][li][g * 8]);
        short8 A2D = *reinterpret_cast<const short8*>(&Ps[w][3][li][32 + g * 8]);
        if (i + 1 < ntile) {
            sphase(i + 1);               // overwrites Ps AFTER the reg-reads above
            kload(i + 2);                // refill single K buffer (clamped)
        }
        f32x4 lt;
        lt = __builtin_amdgcn_mfma_f32_16x16x32_bf16(A1A, ones, z4, 0, 0, 0);
        lt = __builtin_amdgcn_mfma_f32_16x16x32_bf16(A2A, ones, lt, 0, 0, 0);
#pragma unroll
        for (int r = 0; r < 4; ++r) l4A[r] += lt[r];
        lt = __builtin_amdgcn_mfma_f32_16x16x32_bf16(A1B, ones, z4, 0, 0, 0);
        lt = __builtin_amdgcn_mfma_f32_16x16x32_bf16(A2B, ones, lt, 0, 0, 0);
#pragma unroll
        for (int r = 0; r < 4; ++r) l4B[r] += lt[r];
        lt = __builtin_amdgcn_mfma_f32_16x16x32_bf16(A1C, ones, z4, 0, 0, 0);
        lt = __builtin_amdgcn_mfma_f32_16x16x32_bf16(A2C, ones, lt, 0, 0, 0);
#pragma unroll
        for (int r = 0; r < 4; ++r) l4C[r] += lt[r];
        lt = __builtin_amdgcn_mfma_f32_16x16x32_bf16(A1D, ones, z4, 0, 0, 0);
        lt = __builtin_amdgcn_mfma_f32_16x16x32_bf16(A2D, ones, lt, 0, 0, 0);
#pragma unroll
        for (int r = 0; r < 4; ++r) l4D[r] += lt[r];
#pragma unroll
        for (int ds = 0; ds < 4; ++ds) {
            O[ds]      = __builtin_amdgcn_mfma_f32_16x16x32_bf16(A1A, vf[2*ds],   O[ds],      0, 0, 0);
            O[ds]      = __builtin_amdgcn_mfma_f32_16x16x32_bf16(A2A, vf[2*ds+1], O[ds],      0, 0, 0);
            O[4 + ds]  = __builtin_amdgcn_mfma_f32_16x16x32_bf16(A1B, vf[2*ds],   O[4 + ds],  0, 0, 0);
            O[4 + ds]  = __builtin_amdgcn_mfma_f32_16x16x32_bf16(A2B, vf[2*ds+1], O[4 + ds],  0, 0, 0);
            O[8 + ds]  = __builtin_amdgcn_mfma_f32_16x16x32_bf16(A1C, vf[2*ds],   O[8 + ds],  0, 0, 0);
            O[8 + ds]  = __builtin_amdgcn_mfma_f32_16x16x32_bf16(A2C, vf[2*ds+1], O[8 + ds],  0, 0, 0);
            O[12 + ds] = __builtin_amdgcn_mfma_f32_16x16x32_bf16(A1D, vf[2*ds],   O[12 + ds], 0, 0, 0);
            O[12 + ds] = __builtin_amdgcn_mfma_f32_16x16x32_bf16(A2D, vf[2*ds+1], O[12 + ds], 0, 0, 0);
        }
    }

    // ---- per-wave epilogue: two 32-row passes through this wave's Ps region ----
    {
        float* Of = reinterpret_cast<float*>(&Ps[w][0][0][0]);
        float* Lf = Of + 2112;
        const int r32 = l >> 1;          // 0..31: output row within pass
        const int h   = l & 1;           // column half (32 cols)
#pragma unroll
        for (int p = 0; p < 2; ++p) {
#pragma unroll
            for (int tile = 0; tile < 2; ++tile)
#pragma unroll
                for (int ds = 0; ds < 4; ++ds)
#pragma unroll
                    for (int r = 0; r < 4; ++r)
                        Of[(tile * 16 + g4 + r) * 66 + ds * 16 + li] =
                            O[(p * 2 + tile) * 4 + ds][r];
            if (li == 0) {
#pragma unroll
                for (int r = 0; r < 4; ++r) {
                    Lf[g4 + r]      = p ? l4C[r] : l4A[r];
                    Lf[16 + g4 + r] = p ? l4D[r] : l4B[r];
                }
            }
            float v[32];
#pragma unroll
            for (int j = 0; j < 8; ++j) {
                float4 f = *reinterpret_cast<const float4*>(&Of[r32 * 66 + h * 32 + j * 4]);
                v[4*j] = f.x; v[4*j+1] = f.y; v[4*j+2] = f.z; v[4*j+3] = f.w;
            }
            if (single) {
                const float L = Lf[r32];
                const float rl = (L > 0.f) ? 1.f / L : 0.f;
#pragma unroll
                for (int j = 0; j < 32; ++j) v[j] *= rl;
                const long row = (long)(b * SEQ + q0 + p * 32 + r32);
                if (flag) {
                    u16* dst = (u16*)out + row * HD + h * 32;
#pragma unroll
                    for (int jj = 0; jj < 4; ++jj) {
                        uint4 st = make_uint4(pkbf(v[8*jj],   v[8*jj+1]), pkbf(v[8*jj+2], v[8*jj+3]),
                                              pkbf(v[8*jj+4], v[8*jj+5]), pkbf(v[8*jj+6], v[8*jj+7]));
                        *reinterpret_cast<uint4*>(dst + jj * 8) = st;
                    }
                } else {
                    float* dst = (float*)out + row * HD + h * 32;
#pragma unroll
                    for (int jj = 0; jj < 8; ++jj)
                        *reinterpret_cast<float4*>(dst + jj * 4) =
                            make_float4(v[4*jj], v[4*jj+1], v[4*jj+2], v[4*jj+3]);
                }
            } else {
                const int slotIdx = ((b * 72 + chunk_off(qt256) + c) * 8 + w * 2 + p);
                char* slot = part + (long)slotIdx * PSLOTB;
                u16* dst = (u16*)slot + r32 * 64 + h * 32;
#pragma unroll
                for (int jj = 0; jj < 4; ++jj) {
                    uint4 st = make_uint4(pkbf(v[8*jj],   v[8*jj+1]), pkbf(v[8*jj+2], v[8*jj+3]),
                                          pkbf(v[8*jj+4], v[8*jj+5]), pkbf(v[8*jj+6], v[8*jj+7]));
                    *reinterpret_cast<uint4*>(dst + jj * 8) = st;
                }
                if (l < 32)
                    *reinterpret_cast<float*>(slot + 4096 + l * 4) = Lf[l];
            }
        }
    }
}

// ---------------- merge split-K partials (qt256 >= 2): plain sum ----------
__global__ __launch_bounds__(256) void merge_kernel(
    const u32* __restrict__ xs, const char* __restrict__ part,
    void* __restrict__ out)
{
    const int flag = sniff_bf16(xs);
    const int bid = blockIdx.x;         // 448
    const int b = bid & 3;
    const int u = bid >> 2;             // 0..111
    const int qt256 = 2 + u / 8;        // 2..15
    const int v8 = u % 8;
    const int w = v8 >> 1;              // wave 0..3
    const int p = v8 & 1;               // half-pass 0..1
    const int nc = (qt256 >> 1) + 1;    // 2..8 chunks
    const int t  = threadIdx.x;
    const int qq = t >> 3;              // 0..31
    const int dd = (t & 7) * 8;         // 0..56
    const char* s0 = part +
        ((long)((b * 72 + chunk_off(qt256)) * 8 + w * 2 + p)) * PSLOTB;
    float L = 0.f;
    float a8[8];
#pragma unroll
    for (int j = 0; j < 8; ++j) a8[j] = 0.f;
    for (int c = 0; c < nc; ++c) {
        const char* sc = s0 + (long)c * 8 * PSLOTB;   // c-stride = 8 slots
        L += *reinterpret_cast<const float*>(sc + 4096 + qq * 4);
        ushort4 x0 = *reinterpret_cast<const ushort4*>((const u16*)sc + qq * 64 + dd);
        ushort4 x1 = *reinterpret_cast<const ushort4*>((const u16*)sc + qq * 64 + dd + 4);
        a8[0] += bfbits2f(x0.x); a8[1] += bfbits2f(x0.y);
        a8[2] += bfbits2f(x0.z); a8[3] += bfbits2f(x0.w);
        a8[4] += bfbits2f(x1.x); a8[5] += bfbits2f(x1.y);
        a8[6] += bfbits2f(x1.z); a8[7] += bfbits2f(x1.w);
    }
    const float rl = (L > 0.f) ? 1.f / L : 0.f;
#pragma unroll
    for (int j = 0; j < 8; ++j) a8[j] *= rl;
    const long row = (long)(b * SEQ + qt256 * 256 + w * 64 + p * 32 + qq);
    if (flag) {
        uint4 st = make_uint4(pkbf(a8[0], a8[1]), pkbf(a8[2], a8[3]),
                              pkbf(a8[4], a8[5]), pkbf(a8[6], a8[7]));
        *reinterpret_cast<uint4*>((u16*)out + row * HD + dd) = st;
    } else {
        *reinterpret_cast<float4*>((float*)out + row * HD + dd) =
            make_float4(a8[0], a8[1], a8[2], a8[3]);
        *reinterpret_cast<float4*>((float*)out + row * HD + dd + 4) =
            make_float4(a8[4], a8[5], a8[6], a8[7]);
    }
}

extern "C" void kernel_launch(void* const* d_in, const int* in_sizes, int n_in,
                              void* d_out, int out_size, void* d_ws, size_t ws_size,
                              hipStream_t stream) {
    const void* x   = d_in[0];
    const int* mask = (const int*)d_in[1];
    const void* wq  = d_in[2];
    const void* wk  = d_in[3];
    const void* wv  = d_in[4];
    const u32* xs   = (const u32*)x;

    u16* q    = (u16*)d_ws;                          // 2 MB
    u16* k    = q  + (long)NROW * HD;                // 2 MB (fragment-major tiles)
    u16* vp   = k  + (long)NROW * HD;                // 2 MB (fragment-major tiles)
    u32* mb   = (u32*)(vp + (long)NROW * HD);        // 2 KB
    char* part = (char*)(mb + 512);                  // 2304 slots = 9.73 MB
    u16* wb   = (u16*)(part + (long)NSLOT * PSLOTB); // 288 KB bf16 W

    wconv_kernel<<<72, 256, 0, stream>>>(xs, wq, wk, wv, wb);
    qkv_kernel  <<<258, 512, 0, stream>>>(x, wb, mask, q, k, vp, mb);
    attn_kernel <<<288, 256, 0, stream>>>(xs, q, k, vp, mb, part, d_out);
    merge_kernel<<<448, 256, 0, stream>>>(xs, part, d_out);
}